// Round 1
// baseline (467.570 us; speedup 1.0000x reference)
//
#include <hip/hip_runtime.h>
#include <hip/hip_fp16.h>

#define NPTS 262144
#define FDIM 64

// ---------- break-finding kernel ----------
// break1 = first index with d > 1.5 (else 0); break2 = first with d > 2.0 (else 0).
// ws[0..1] pre-memset to 0xFFFFFFFF; sentinel >= NPTS means "none found" -> 0 (applied by consumer).
__global__ __launch_bounds__(256) void break_kernel(const float* __restrict__ x,
                                                    const float* __restrict__ rays_o,
                                                    const float* __restrict__ scale,
                                                    unsigned* __restrict__ breaks) {
  const unsigned t = blockIdx.x * 256u + threadIdx.x;  // 256 blocks x 256 threads
  const float r0 = rays_o[0], r1 = rays_o[1], r2 = rays_o[2];
  const float s0 = scale[0], s1 = scale[1], s2 = scale[2];
  unsigned b1 = 0xFFFFFFFFu, b2 = 0xFFFFFFFFu;
  for (unsigned p = t; p < NPTS; p += 65536u) {
    const float dx = r0 - x[p * 3 + 0] * s0;
    const float dy = r1 - x[p * 3 + 1] * s1;
    const float dz = r2 - x[p * 3 + 2] * s2;
    // match reference order: (dx^2 + dy^2) + dz^2, no fma contraction
    const float d = sqrtf(__fadd_rn(__fadd_rn(__fmul_rn(dx, dx), __fmul_rn(dy, dy)),
                                    __fmul_rn(dz, dz)));
    if (d > 1.5f) b1 = min(b1, p);
    if (d > 2.0f) b2 = min(b2, p);
  }
  __shared__ unsigned sb1[256];
  __shared__ unsigned sb2[256];
  sb1[threadIdx.x] = b1;
  sb2[threadIdx.x] = b2;
  __syncthreads();
  for (int s = 128; s > 0; s >>= 1) {
    if ((int)threadIdx.x < s) {
      sb1[threadIdx.x] = min(sb1[threadIdx.x], sb1[threadIdx.x + s]);
      sb2[threadIdx.x] = min(sb2[threadIdx.x], sb2[threadIdx.x + s]);
    }
    __syncthreads();
  }
  if (threadIdx.x == 0) {
    atomicMin(&breaks[0], sb1[0]);
    atomicMin(&breaks[1], sb2[0]);
  }
}

// ---------- transpose [C][S][S] fp32 -> [S*S][C] fp16 ----------
// Block handles a tile of 64 channels x 64 linear pixels via LDS (stride 66 halves:
// worst aliasing is 2-way, free on gfx950).
__global__ __launch_bounds__(256) void transpose_kernel(const float* __restrict__ src,
                                                        __half* __restrict__ dst, int S) {
  __shared__ __half lds[64 * 66];
  const int t = threadIdx.x;
  const size_t SS = (size_t)S * S;
  const size_t p0 = (size_t)blockIdx.x * 64;
#pragma unroll
  for (int it = 0; it < 16; ++it) {
    const int c = it * 4 + (t >> 6);
    const int px = t & 63;
    const float v = src[(size_t)c * SS + p0 + px];  // coalesced read along pixels
    lds[px * 66 + c] = __float2half(v);
  }
  __syncthreads();
#pragma unroll
  for (int it = 0; it < 16; ++it) {
    const int px = it * 4 + (t >> 6);
    const int c = t & 63;
    dst[(p0 + px) * FDIM + c] = lds[px * 66 + c];   // coalesced write along channels
  }
}

// ---------- bilinear sampling helpers ----------
union H8 { uint4 u; __half h[8]; };

__device__ __forceinline__ void bilinear_weights(int W, float cx, float cy,
                                                 float& w00, float& w01, float& w10, float& w11,
                                                 int& xc0, int& xc1, int& yc0, int& yc1) {
  const float Wm1 = (float)(W - 1);
  const float fx = (cx + 1.0f) * 0.5f * Wm1;
  const float fy = (cy + 1.0f) * 0.5f * Wm1;
  const float x0f = floorf(fx), y0f = floorf(fy);
  const float wx = fx - x0f, wy = fy - y0f;
  const int ix = (int)x0f, iy = (int)y0f;
  const int ix1 = ix + 1, iy1 = iy + 1;
  const bool vx0 = (ix >= 0) && (ix < W);
  const bool vx1 = (ix1 >= 0) && (ix1 < W);
  const bool vy0 = (iy >= 0) && (iy < W);
  const bool vy1 = (iy1 >= 0) && (iy1 < W);
  xc0 = min(max(ix, 0), W - 1);
  xc1 = min(max(ix1, 0), W - 1);
  yc0 = min(max(iy, 0), W - 1);
  yc1 = min(max(iy1, 0), W - 1);
  w00 = (1.0f - wx) * (1.0f - wy) * (float)(vx0 && vy0);
  w01 = wx * (1.0f - wy) * (float)(vx1 && vy0);
  w10 = (1.0f - wx) * wy * (float)(vx0 && vy1);
  w11 = wx * wy * (float)(vx1 && vy1);
}

// fp16 [H][W][C] sampler: 8 channels per thread starting at j8
__device__ __forceinline__ void sample8_t(const __half* __restrict__ pl, int W,
                                          float cx, float cy, int j8, float acc[8]) {
  float w00, w01, w10, w11;
  int xc0, xc1, yc0, yc1;
  bilinear_weights(W, cx, cy, w00, w01, w10, w11, xc0, xc1, yc0, yc1);
  const __half* b00 = pl + ((size_t)(yc0 * W + xc0) * FDIM + j8);
  const __half* b01 = pl + ((size_t)(yc0 * W + xc1) * FDIM + j8);
  const __half* b10 = pl + ((size_t)(yc1 * W + xc0) * FDIM + j8);
  const __half* b11 = pl + ((size_t)(yc1 * W + xc1) * FDIM + j8);
  H8 v00, v01, v10, v11;
  v00.u = *(const uint4*)b00;
  v01.u = *(const uint4*)b01;
  v10.u = *(const uint4*)b10;
  v11.u = *(const uint4*)b11;
#pragma unroll
  for (int k = 0; k < 8; ++k) {
    acc[k] += w00 * __half2float(v00.h[k]) + w01 * __half2float(v01.h[k]) +
              w10 * __half2float(v10.h[k]) + w11 * __half2float(v11.h[k]);
  }
}

// fp32 [C][H][W] direct sampler (fallback when workspace is too small)
__device__ __forceinline__ void sample8_d(const float* __restrict__ pl, int W,
                                          float cx, float cy, int j8, float acc[8]) {
  float w00, w01, w10, w11;
  int xc0, xc1, yc0, yc1;
  bilinear_weights(W, cx, cy, w00, w01, w10, w11, xc0, xc1, yc0, yc1);
  const size_t SS = (size_t)W * W;
  const int i00 = yc0 * W + xc0, i01 = yc0 * W + xc1;
  const int i10 = yc1 * W + xc0, i11 = yc1 * W + xc1;
#pragma unroll
  for (int k = 0; k < 8; ++k) {
    const size_t co = (size_t)(j8 + k) * SS;
    acc[k] += w00 * pl[co + i00] + w01 * pl[co + i01] +
              w10 * pl[co + i10] + w11 * pl[co + i11];
  }
}

struct PlanesH { const __half* p[9]; };   // [level*3 + orient], orient: 0=xy,1=yz,2=xz
struct PlanesF { const float* p[9]; };

// ---------- main sampling kernel (fp16 transposed planes) ----------
__global__ __launch_bounds__(256) void sample_kernel(const float* __restrict__ x,
                                                     const float* __restrict__ scale,
                                                     const unsigned* __restrict__ breaks,
                                                     PlanesH tp, float* __restrict__ out) {
  const int t = blockIdx.x * 256 + threadIdx.x;   // exact grid: NPTS*8 threads
  const int p = t >> 3;
  const int j8 = (t & 7) * 8;
  const float s0 = scale[0], s1 = scale[1], s2 = scale[2];
  const float xs0 = x[p * 3 + 0] * s0;
  const float xs1 = x[p * 3 + 1] * s1;
  const float xs2 = x[p * 3 + 2] * s2;
  unsigned b1 = breaks[0]; if (b1 >= NPTS) b1 = 0;
  unsigned b2 = breaks[1]; if (b2 >= NPTS) b2 = 0;
  const unsigned pu = (unsigned)p;
  const int level = (pu < b1) ? 0 : ((pu < b2) ? 1 : 2);
  float acc[8];
#pragma unroll
  for (int k = 0; k < 8; ++k) acc[k] = 0.0f;
  // level 0 always
  sample8_t(tp.p[0], 512, xs0, xs1, j8, acc);  // xy: (x,y)
  sample8_t(tp.p[1], 512, xs1, xs2, j8, acc);  // yz: (y,z)
  sample8_t(tp.p[2], 512, xs0, xs2, j8, acc);  // xz: (x,z)
  if (level >= 1) {
    sample8_t(tp.p[3], 256, xs0, xs1, j8, acc);
    sample8_t(tp.p[4], 256, xs1, xs2, j8, acc);
    sample8_t(tp.p[5], 256, xs0, xs2, j8, acc);
  }
  if (level >= 2) {
    sample8_t(tp.p[6], 128, xs0, xs1, j8, acc);
    sample8_t(tp.p[7], 128, xs1, xs2, j8, acc);
    sample8_t(tp.p[8], 128, xs0, xs2, j8, acc);
  }
  float4* o4 = (float4*)(out + (size_t)p * FDIM + j8);
  o4[0] = make_float4(acc[0], acc[1], acc[2], acc[3]);
  o4[1] = make_float4(acc[4], acc[5], acc[6], acc[7]);
}

// ---------- fallback: sample directly from fp32 [C][H][W] ----------
__global__ __launch_bounds__(256) void sample_kernel_direct(const float* __restrict__ x,
                                                            const float* __restrict__ scale,
                                                            const unsigned* __restrict__ breaks,
                                                            PlanesF tp, float* __restrict__ out) {
  const int t = blockIdx.x * 256 + threadIdx.x;
  const int p = t >> 3;
  const int j8 = (t & 7) * 8;
  const float s0 = scale[0], s1 = scale[1], s2 = scale[2];
  const float xs0 = x[p * 3 + 0] * s0;
  const float xs1 = x[p * 3 + 1] * s1;
  const float xs2 = x[p * 3 + 2] * s2;
  unsigned b1 = breaks[0]; if (b1 >= NPTS) b1 = 0;
  unsigned b2 = breaks[1]; if (b2 >= NPTS) b2 = 0;
  const unsigned pu = (unsigned)p;
  const int level = (pu < b1) ? 0 : ((pu < b2) ? 1 : 2);
  float acc[8];
#pragma unroll
  for (int k = 0; k < 8; ++k) acc[k] = 0.0f;
  sample8_d(tp.p[0], 512, xs0, xs1, j8, acc);
  sample8_d(tp.p[1], 512, xs1, xs2, j8, acc);
  sample8_d(tp.p[2], 512, xs0, xs2, j8, acc);
  if (level >= 1) {
    sample8_d(tp.p[3], 256, xs0, xs1, j8, acc);
    sample8_d(tp.p[4], 256, xs1, xs2, j8, acc);
    sample8_d(tp.p[5], 256, xs0, xs2, j8, acc);
  }
  if (level >= 2) {
    sample8_d(tp.p[6], 128, xs0, xs1, j8, acc);
    sample8_d(tp.p[7], 128, xs1, xs2, j8, acc);
    sample8_d(tp.p[8], 128, xs0, xs2, j8, acc);
  }
  float4* o4 = (float4*)(out + (size_t)p * FDIM + j8);
  o4[0] = make_float4(acc[0], acc[1], acc[2], acc[3]);
  o4[1] = make_float4(acc[4], acc[5], acc[6], acc[7]);
}

extern "C" void kernel_launch(void* const* d_in, const int* in_sizes, int n_in,
                              void* d_out, int out_size, void* d_ws, size_t ws_size,
                              hipStream_t stream) {
  const float* x = (const float*)d_in[0];
  const float* rays_o = (const float*)d_in[1];
  const float* scale = (const float*)d_in[2];
  // setup_inputs order per level: xy, yz, xz
  const float* pl32[9];
  for (int i = 0; i < 9; ++i) pl32[i] = (const float*)d_in[3 + i];
  float* out = (float*)d_out;

  unsigned char* ws = (unsigned char*)d_ws;
  unsigned* breaks = (unsigned*)ws;

  // breaks init to UINT_MAX sentinel
  hipMemsetAsync(d_ws, 0xFF, 8, stream);
  break_kernel<<<256, 256, 0, stream>>>(x, rays_o, scale, breaks);

  const int Ss[3] = {512, 256, 128};
  size_t need = 256;
  for (int l = 0; l < 3; ++l) need += 3 * (size_t)Ss[l] * Ss[l] * FDIM * sizeof(__half);

  if (ws_size >= need) {
    PlanesH tp;
    size_t off = 256;
    for (int l = 0; l < 3; ++l) {
      const int S = Ss[l];
      const int SS = S * S;
      for (int o = 0; o < 3; ++o) {
        __half* dst = (__half*)(ws + off);
        tp.p[l * 3 + o] = dst;
        transpose_kernel<<<SS / 64, 256, 0, stream>>>(pl32[l * 3 + o], dst, S);
        off += (size_t)SS * FDIM * sizeof(__half);
      }
    }
    sample_kernel<<<(NPTS * 8) / 256, 256, 0, stream>>>(x, scale, breaks, tp, out);
  } else {
    PlanesF tf;
    for (int i = 0; i < 9; ++i) tf.p[i] = pl32[i];
    sample_kernel_direct<<<(NPTS * 8) / 256, 256, 0, stream>>>(x, scale, breaks, tf, out);
  }
}

// Round 3
// 446.208 us; speedup vs baseline: 1.0479x; 1.0479x over previous
//
#include <hip/hip_runtime.h>
#include <hip/hip_fp16.h>

#define NPTS 262144
#define FDIM 64

typedef float vfloat4 __attribute__((ext_vector_type(4)));

// ---------- break-finding kernel ----------
// break1 = first index with d > 1.5 (else 0); break2 = first with d > 2.0 (else 0).
// ws[0..1] pre-memset to 0xFFFFFFFF; sentinel >= NPTS means "none found" -> 0 (applied by consumer).
__global__ __launch_bounds__(256) void break_kernel(const float* __restrict__ x,
                                                    const float* __restrict__ rays_o,
                                                    const float* __restrict__ scale,
                                                    unsigned* __restrict__ breaks) {
  const unsigned t = blockIdx.x * 256u + threadIdx.x;  // 256 blocks x 256 threads
  const float r0 = rays_o[0], r1 = rays_o[1], r2 = rays_o[2];
  const float s0 = scale[0], s1 = scale[1], s2 = scale[2];
  unsigned b1 = 0xFFFFFFFFu, b2 = 0xFFFFFFFFu;
  for (unsigned p = t; p < NPTS; p += 65536u) {
    const float dx = r0 - x[p * 3 + 0] * s0;
    const float dy = r1 - x[p * 3 + 1] * s1;
    const float dz = r2 - x[p * 3 + 2] * s2;
    // match reference order: (dx^2 + dy^2) + dz^2, no fma contraction
    const float d = sqrtf(__fadd_rn(__fadd_rn(__fmul_rn(dx, dx), __fmul_rn(dy, dy)),
                                    __fmul_rn(dz, dz)));
    if (d > 1.5f) b1 = min(b1, p);
    if (d > 2.0f) b2 = min(b2, p);
  }
  __shared__ unsigned sb1[256];
  __shared__ unsigned sb2[256];
  sb1[threadIdx.x] = b1;
  sb2[threadIdx.x] = b2;
  __syncthreads();
  for (int s = 128; s > 0; s >>= 1) {
    if ((int)threadIdx.x < s) {
      sb1[threadIdx.x] = min(sb1[threadIdx.x], sb1[threadIdx.x + s]);
      sb2[threadIdx.x] = min(sb2[threadIdx.x], sb2[threadIdx.x + s]);
    }
    __syncthreads();
  }
  if (threadIdx.x == 0) {
    atomicMin(&breaks[0], sb1[0]);
    atomicMin(&breaks[1], sb2[0]);
  }
}

// ---------- fused transpose: 9x [C][S][S] fp32 -> [S*S][C] fp16 ----------
// Tile = 64 channels x 64 linear pixels. Vectorized: float4 global reads
// (1 KB/wave-inst), uint4 global writes (1 KB/wave-inst). LDS pixel-major
// [64 px][66 ch] halves; output-phase b32 reads are 2-way aliased (free).
struct TransposeArgs {
  const float* src[9];
  __half* dst[9];
  int tile_hi[9];  // exclusive prefix sum of tiles per plane
  int SS[9];
};

__global__ __launch_bounds__(256) void transpose_all(TransposeArgs a) {
  __shared__ __half lds[64 * 66];
  const int tile = blockIdx.x;
  int pi = 0;
#pragma unroll
  for (int i = 0; i < 9; ++i) {
    if (tile >= a.tile_hi[i]) pi = i + 1;
  }
  const int lo = (pi == 0) ? 0 : a.tile_hi[pi - 1];
  const float* __restrict__ src = a.src[pi];
  __half* __restrict__ dst = a.dst[pi];
  const size_t SS = (size_t)a.SS[pi];
  const size_t p0 = (size_t)(tile - lo) * 64;

  const int t = threadIdx.x;
  // Phase 1: global float4 reads -> LDS halves. 4 iters x (16 ch x 64 px).
  const int px4 = t & 15;          // which float4 within the 64-px row
  const int cg = t >> 4;           // channel within group of 16
#pragma unroll
  for (int it = 0; it < 4; ++it) {
    const int c = it * 16 + cg;
    const float4 v = *(const float4*)(src + (size_t)c * SS + p0 + (size_t)px4 * 4);
    lds[(px4 * 4 + 0) * 66 + c] = __float2half(v.x);
    lds[(px4 * 4 + 1) * 66 + c] = __float2half(v.y);
    lds[(px4 * 4 + 2) * 66 + c] = __float2half(v.z);
    lds[(px4 * 4 + 3) * 66 + c] = __float2half(v.w);
  }
  __syncthreads();
  // Phase 2: LDS -> global uint4 (8 halves). 2 iters x (32 px x 8 ch-groups).
  const int c8 = t & 7;
  const int pxo = t >> 3;          // 0..31
#pragma unroll
  for (int it = 0; it < 2; ++it) {
    const int px = it * 32 + pxo;
    const unsigned* w = (const unsigned*)(lds + px * 66 + c8 * 8);  // 4B-aligned
    uint4 v;
    v.x = w[0]; v.y = w[1]; v.z = w[2]; v.w = w[3];
    *(uint4*)(dst + (p0 + (size_t)px) * FDIM + c8 * 8) = v;         // 16B-aligned
  }
}

// ---------- bilinear sampling helpers ----------
union H8 { uint4 u; __half h[8]; };

__device__ __forceinline__ void bilinear_weights(int W, float cx, float cy,
                                                 float& w00, float& w01, float& w10, float& w11,
                                                 int& xc0, int& xc1, int& yc0, int& yc1) {
  const float Wm1 = (float)(W - 1);
  const float fx = (cx + 1.0f) * 0.5f * Wm1;
  const float fy = (cy + 1.0f) * 0.5f * Wm1;
  const float x0f = floorf(fx), y0f = floorf(fy);
  const float wx = fx - x0f, wy = fy - y0f;
  const int ix = (int)x0f, iy = (int)y0f;
  const int ix1 = ix + 1, iy1 = iy + 1;
  const bool vx0 = (ix >= 0) && (ix < W);
  const bool vx1 = (ix1 >= 0) && (ix1 < W);
  const bool vy0 = (iy >= 0) && (iy < W);
  const bool vy1 = (iy1 >= 0) && (iy1 < W);
  xc0 = min(max(ix, 0), W - 1);
  xc1 = min(max(ix1, 0), W - 1);
  yc0 = min(max(iy, 0), W - 1);
  yc1 = min(max(iy1, 0), W - 1);
  w00 = (1.0f - wx) * (1.0f - wy) * (float)(vx0 && vy0);
  w01 = wx * (1.0f - wy) * (float)(vx1 && vy0);
  w10 = (1.0f - wx) * wy * (float)(vx0 && vy1);
  w11 = wx * wy * (float)(vx1 && vy1);
}

// fp16 [H][W][C] sampler: 8 channels per thread starting at j8
__device__ __forceinline__ void sample8_t(const __half* __restrict__ pl, int W,
                                          float cx, float cy, int j8, float acc[8]) {
  float w00, w01, w10, w11;
  int xc0, xc1, yc0, yc1;
  bilinear_weights(W, cx, cy, w00, w01, w10, w11, xc0, xc1, yc0, yc1);
  const __half* b00 = pl + ((size_t)(yc0 * W + xc0) * FDIM + j8);
  const __half* b01 = pl + ((size_t)(yc0 * W + xc1) * FDIM + j8);
  const __half* b10 = pl + ((size_t)(yc1 * W + xc0) * FDIM + j8);
  const __half* b11 = pl + ((size_t)(yc1 * W + xc1) * FDIM + j8);
  H8 v00, v01, v10, v11;
  v00.u = *(const uint4*)b00;
  v01.u = *(const uint4*)b01;
  v10.u = *(const uint4*)b10;
  v11.u = *(const uint4*)b11;
#pragma unroll
  for (int k = 0; k < 8; ++k) {
    acc[k] += w00 * __half2float(v00.h[k]) + w01 * __half2float(v01.h[k]) +
              w10 * __half2float(v10.h[k]) + w11 * __half2float(v11.h[k]);
  }
}

// fp32 [C][H][W] direct sampler (fallback when workspace is too small)
__device__ __forceinline__ void sample8_d(const float* __restrict__ pl, int W,
                                          float cx, float cy, int j8, float acc[8]) {
  float w00, w01, w10, w11;
  int xc0, xc1, yc0, yc1;
  bilinear_weights(W, cx, cy, w00, w01, w10, w11, xc0, xc1, yc0, yc1);
  const size_t SS = (size_t)W * W;
  const int i00 = yc0 * W + xc0, i01 = yc0 * W + xc1;
  const int i10 = yc1 * W + xc0, i11 = yc1 * W + xc1;
#pragma unroll
  for (int k = 0; k < 8; ++k) {
    const size_t co = (size_t)(j8 + k) * SS;
    acc[k] += w00 * pl[co + i00] + w01 * pl[co + i01] +
              w10 * pl[co + i10] + w11 * pl[co + i11];
  }
}

struct PlanesH { const __half* p[9]; };   // [level*3 + orient], orient: 0=xy,1=yz,2=xz
struct PlanesF { const float* p[9]; };

// ---------- main sampling kernel (fp16 transposed planes) ----------
__global__ __launch_bounds__(256) void sample_kernel(const float* __restrict__ x,
                                                     const float* __restrict__ scale,
                                                     const unsigned* __restrict__ breaks,
                                                     PlanesH tp, float* __restrict__ out) {
  const int t = blockIdx.x * 256 + threadIdx.x;   // exact grid: NPTS*8 threads
  const int p = t >> 3;
  const int j8 = (t & 7) * 8;
  const float s0 = scale[0], s1 = scale[1], s2 = scale[2];
  const float xs0 = x[p * 3 + 0] * s0;
  const float xs1 = x[p * 3 + 1] * s1;
  const float xs2 = x[p * 3 + 2] * s2;
  unsigned b1 = breaks[0]; if (b1 >= NPTS) b1 = 0;
  unsigned b2 = breaks[1]; if (b2 >= NPTS) b2 = 0;
  const unsigned pu = (unsigned)p;
  const int level = (pu < b1) ? 0 : ((pu < b2) ? 1 : 2);
  float acc[8];
#pragma unroll
  for (int k = 0; k < 8; ++k) acc[k] = 0.0f;
  // level 0 always
  sample8_t(tp.p[0], 512, xs0, xs1, j8, acc);  // xy: (x,y)
  sample8_t(tp.p[1], 512, xs1, xs2, j8, acc);  // yz: (y,z)
  sample8_t(tp.p[2], 512, xs0, xs2, j8, acc);  // xz: (x,z)
  if (level >= 1) {
    sample8_t(tp.p[3], 256, xs0, xs1, j8, acc);
    sample8_t(tp.p[4], 256, xs1, xs2, j8, acc);
    sample8_t(tp.p[5], 256, xs0, xs2, j8, acc);
  }
  if (level >= 2) {
    sample8_t(tp.p[6], 128, xs0, xs1, j8, acc);
    sample8_t(tp.p[7], 128, xs1, xs2, j8, acc);
    sample8_t(tp.p[8], 128, xs0, xs2, j8, acc);
  }
  float* o = out + (size_t)p * FDIM + j8;
  vfloat4 lo = {acc[0], acc[1], acc[2], acc[3]};
  vfloat4 hi = {acc[4], acc[5], acc[6], acc[7]};
  __builtin_nontemporal_store(lo, (vfloat4*)o);
  __builtin_nontemporal_store(hi, (vfloat4*)(o + 4));
}

// ---------- fallback: sample directly from fp32 [C][H][W] ----------
__global__ __launch_bounds__(256) void sample_kernel_direct(const float* __restrict__ x,
                                                            const float* __restrict__ scale,
                                                            const unsigned* __restrict__ breaks,
                                                            PlanesF tp, float* __restrict__ out) {
  const int t = blockIdx.x * 256 + threadIdx.x;
  const int p = t >> 3;
  const int j8 = (t & 7) * 8;
  const float s0 = scale[0], s1 = scale[1], s2 = scale[2];
  const float xs0 = x[p * 3 + 0] * s0;
  const float xs1 = x[p * 3 + 1] * s1;
  const float xs2 = x[p * 3 + 2] * s2;
  unsigned b1 = breaks[0]; if (b1 >= NPTS) b1 = 0;
  unsigned b2 = breaks[1]; if (b2 >= NPTS) b2 = 0;
  const unsigned pu = (unsigned)p;
  const int level = (pu < b1) ? 0 : ((pu < b2) ? 1 : 2);
  float acc[8];
#pragma unroll
  for (int k = 0; k < 8; ++k) acc[k] = 0.0f;
  sample8_d(tp.p[0], 512, xs0, xs1, j8, acc);
  sample8_d(tp.p[1], 512, xs1, xs2, j8, acc);
  sample8_d(tp.p[2], 512, xs0, xs2, j8, acc);
  if (level >= 1) {
    sample8_d(tp.p[3], 256, xs0, xs1, j8, acc);
    sample8_d(tp.p[4], 256, xs1, xs2, j8, acc);
    sample8_d(tp.p[5], 256, xs0, xs2, j8, acc);
  }
  if (level >= 2) {
    sample8_d(tp.p[6], 128, xs0, xs1, j8, acc);
    sample8_d(tp.p[7], 128, xs1, xs2, j8, acc);
    sample8_d(tp.p[8], 128, xs0, xs2, j8, acc);
  }
  float4* o4 = (float4*)(out + (size_t)p * FDIM + j8);
  o4[0] = make_float4(acc[0], acc[1], acc[2], acc[3]);
  o4[1] = make_float4(acc[4], acc[5], acc[6], acc[7]);
}

extern "C" void kernel_launch(void* const* d_in, const int* in_sizes, int n_in,
                              void* d_out, int out_size, void* d_ws, size_t ws_size,
                              hipStream_t stream) {
  const float* x = (const float*)d_in[0];
  const float* rays_o = (const float*)d_in[1];
  const float* scale = (const float*)d_in[2];
  // setup_inputs order per level: xy, yz, xz
  const float* pl32[9];
  for (int i = 0; i < 9; ++i) pl32[i] = (const float*)d_in[3 + i];
  float* out = (float*)d_out;

  unsigned char* ws = (unsigned char*)d_ws;
  unsigned* breaks = (unsigned*)ws;

  // breaks init to UINT_MAX sentinel
  (void)hipMemsetAsync(d_ws, 0xFF, 8, stream);
  break_kernel<<<256, 256, 0, stream>>>(x, rays_o, scale, breaks);

  const int Ss[3] = {512, 256, 128};
  size_t need = 256;
  for (int l = 0; l < 3; ++l) need += 3 * (size_t)Ss[l] * Ss[l] * FDIM * sizeof(__half);

  if (ws_size >= need) {
    PlanesH tp;
    TransposeArgs ta;
    size_t off = 256;
    int tiles_acc = 0;
    for (int l = 0; l < 3; ++l) {
      const int S = Ss[l];
      const int SS = S * S;
      for (int o = 0; o < 3; ++o) {
        const int i = l * 3 + o;
        __half* dst = (__half*)(ws + off);
        tp.p[i] = dst;
        ta.src[i] = pl32[i];
        ta.dst[i] = dst;
        ta.SS[i] = SS;
        tiles_acc += SS / 64;
        ta.tile_hi[i] = tiles_acc;
        off += (size_t)SS * FDIM * sizeof(__half);
      }
    }
    transpose_all<<<tiles_acc, 256, 0, stream>>>(ta);
    sample_kernel<<<(NPTS * 8) / 256, 256, 0, stream>>>(x, scale, breaks, tp, out);
  } else {
    PlanesF tf;
    for (int i = 0; i < 9; ++i) tf.p[i] = pl32[i];
    sample_kernel_direct<<<(NPTS * 8) / 256, 256, 0, stream>>>(x, scale, breaks, tf, out);
  }
}

// Round 4
// 437.815 us; speedup vs baseline: 1.0680x; 1.0192x over previous
//
#include <hip/hip_runtime.h>
#include <hip/hip_fp16.h>

#define NPTS 262144
#define FDIM 64
#define NCELL 32768  // 32^3 Morton cells

typedef float vfloat4 __attribute__((ext_vector_type(4)));

// ---------- break-finding kernel ----------
__global__ __launch_bounds__(256) void break_kernel(const float* __restrict__ x,
                                                    const float* __restrict__ rays_o,
                                                    const float* __restrict__ scale,
                                                    unsigned* __restrict__ breaks) {
  const unsigned t = blockIdx.x * 256u + threadIdx.x;  // 256 blocks x 256 threads
  const float r0 = rays_o[0], r1 = rays_o[1], r2 = rays_o[2];
  const float s0 = scale[0], s1 = scale[1], s2 = scale[2];
  unsigned b1 = 0xFFFFFFFFu, b2 = 0xFFFFFFFFu;
  for (unsigned p = t; p < NPTS; p += 65536u) {
    const float dx = r0 - x[p * 3 + 0] * s0;
    const float dy = r1 - x[p * 3 + 1] * s1;
    const float dz = r2 - x[p * 3 + 2] * s2;
    const float d = sqrtf(__fadd_rn(__fadd_rn(__fmul_rn(dx, dx), __fmul_rn(dy, dy)),
                                    __fmul_rn(dz, dz)));
    if (d > 1.5f) b1 = min(b1, p);
    if (d > 2.0f) b2 = min(b2, p);
  }
  __shared__ unsigned sb1[256];
  __shared__ unsigned sb2[256];
  sb1[threadIdx.x] = b1;
  sb2[threadIdx.x] = b2;
  __syncthreads();
  for (int s = 128; s > 0; s >>= 1) {
    if ((int)threadIdx.x < s) {
      sb1[threadIdx.x] = min(sb1[threadIdx.x], sb1[threadIdx.x + s]);
      sb2[threadIdx.x] = min(sb2[threadIdx.x], sb2[threadIdx.x + s]);
    }
    __syncthreads();
  }
  if (threadIdx.x == 0) {
    atomicMin(&breaks[0], sb1[0]);
    atomicMin(&breaks[1], sb2[0]);
  }
}

// ---------- Morton cell key ----------
__device__ __forceinline__ unsigned part5(unsigned v) {
  v &= 31u;
  v = (v | (v << 8)) & 0x100Fu;
  v = (v | (v << 4)) & 0x10C3u;
  v = (v | (v << 2)) & 0x1249u;
  return v;
}

__device__ __forceinline__ unsigned cell_key(float x0, float x1, float x2) {
  const int cx = min(max((int)((x0 + 1.0f) * 16.0f), 0), 31);
  const int cy = min(max((int)((x1 + 1.0f) * 16.0f), 0), 31);
  const int cz = min(max((int)((x2 + 1.0f) * 16.0f), 0), 31);
  return part5((unsigned)cx) | (part5((unsigned)cy) << 1) | (part5((unsigned)cz) << 2);
}

// ---------- counting-sort kernels ----------
__global__ __launch_bounds__(256) void hist_kernel(const float* __restrict__ x,
                                                   const float* __restrict__ scale,
                                                   unsigned* __restrict__ hist) {
  const unsigned t = blockIdx.x * 256u + threadIdx.x;  // NPTS threads
  const float s0 = scale[0], s1 = scale[1], s2 = scale[2];
  const unsigned key = cell_key(x[t * 3 + 0] * s0, x[t * 3 + 1] * s1, x[t * 3 + 2] * s2);
  atomicAdd(&hist[key], 1u);
}

__global__ __launch_bounds__(256) void scan_kernel(unsigned* __restrict__ hist) {
  const int tid = threadIdx.x;  // single block of 256; 128 cells per thread
  unsigned s = 0;
  for (int i = 0; i < 128; ++i) s += hist[tid * 128 + i];
  __shared__ unsigned ls[256];
  ls[tid] = s;
  __syncthreads();
  for (int d = 1; d < 256; d <<= 1) {
    const unsigned add = (tid >= d) ? ls[tid - d] : 0u;
    __syncthreads();
    ls[tid] += add;
    __syncthreads();
  }
  unsigned run = ls[tid] - s;  // exclusive base for this chunk
  for (int i = 0; i < 128; ++i) {
    const unsigned h = hist[tid * 128 + i];
    hist[tid * 128 + i] = run;
    run += h;
  }
}

__global__ __launch_bounds__(256) void scatter_kernel(const float* __restrict__ x,
                                                      const float* __restrict__ scale,
                                                      unsigned* __restrict__ offs,
                                                      unsigned* __restrict__ order) {
  const unsigned t = blockIdx.x * 256u + threadIdx.x;  // NPTS threads
  const float s0 = scale[0], s1 = scale[1], s2 = scale[2];
  const unsigned key = cell_key(x[t * 3 + 0] * s0, x[t * 3 + 1] * s1, x[t * 3 + 2] * s2);
  const unsigned pos = atomicAdd(&offs[key], 1u);
  order[pos] = t;
}

// ---------- fused transpose: 9x [C][S][S] fp32 -> [S*S][C] fp16 ----------
struct TransposeArgs {
  const float* src[9];
  __half* dst[9];
  int tile_hi[9];  // inclusive prefix sum of tiles per plane
  int SS[9];
};

__global__ __launch_bounds__(256) void transpose_all(TransposeArgs a) {
  __shared__ __half lds[64 * 66];
  const int tile = blockIdx.x;
  int pi = 0;
#pragma unroll
  for (int i = 0; i < 9; ++i) {
    if (tile >= a.tile_hi[i]) pi = i + 1;
  }
  const int lo = (pi == 0) ? 0 : a.tile_hi[pi - 1];
  const float* __restrict__ src = a.src[pi];
  __half* __restrict__ dst = a.dst[pi];
  const size_t SS = (size_t)a.SS[pi];
  const size_t p0 = (size_t)(tile - lo) * 64;

  const int t = threadIdx.x;
  const int px4 = t & 15;
  const int cg = t >> 4;
#pragma unroll
  for (int it = 0; it < 4; ++it) {
    const int c = it * 16 + cg;
    const float4 v = *(const float4*)(src + (size_t)c * SS + p0 + (size_t)px4 * 4);
    lds[(px4 * 4 + 0) * 66 + c] = __float2half(v.x);
    lds[(px4 * 4 + 1) * 66 + c] = __float2half(v.y);
    lds[(px4 * 4 + 2) * 66 + c] = __float2half(v.z);
    lds[(px4 * 4 + 3) * 66 + c] = __float2half(v.w);
  }
  __syncthreads();
  const int c8 = t & 7;
  const int pxo = t >> 3;
#pragma unroll
  for (int it = 0; it < 2; ++it) {
    const int px = it * 32 + pxo;
    const unsigned* w = (const unsigned*)(lds + px * 66 + c8 * 8);
    uint4 v;
    v.x = w[0]; v.y = w[1]; v.z = w[2]; v.w = w[3];
    *(uint4*)(dst + (p0 + (size_t)px) * FDIM + c8 * 8) = v;
  }
}

// ---------- bilinear sampling helpers ----------
union H8 { uint4 u; __half h[8]; };

__device__ __forceinline__ void bilinear_weights(int W, float cx, float cy,
                                                 float& w00, float& w01, float& w10, float& w11,
                                                 int& xc0, int& xc1, int& yc0, int& yc1) {
  const float Wm1 = (float)(W - 1);
  const float fx = (cx + 1.0f) * 0.5f * Wm1;
  const float fy = (cy + 1.0f) * 0.5f * Wm1;
  const float x0f = floorf(fx), y0f = floorf(fy);
  const float wx = fx - x0f, wy = fy - y0f;
  const int ix = (int)x0f, iy = (int)y0f;
  const int ix1 = ix + 1, iy1 = iy + 1;
  const bool vx0 = (ix >= 0) && (ix < W);
  const bool vx1 = (ix1 >= 0) && (ix1 < W);
  const bool vy0 = (iy >= 0) && (iy < W);
  const bool vy1 = (iy1 >= 0) && (iy1 < W);
  xc0 = min(max(ix, 0), W - 1);
  xc1 = min(max(ix1, 0), W - 1);
  yc0 = min(max(iy, 0), W - 1);
  yc1 = min(max(iy1, 0), W - 1);
  w00 = (1.0f - wx) * (1.0f - wy) * (float)(vx0 && vy0);
  w01 = wx * (1.0f - wy) * (float)(vx1 && vy0);
  w10 = (1.0f - wx) * wy * (float)(vx0 && vy1);
  w11 = wx * wy * (float)(vx1 && vy1);
}

__device__ __forceinline__ void sample8_t(const __half* __restrict__ pl, int W,
                                          float cx, float cy, int j8, float acc[8]) {
  float w00, w01, w10, w11;
  int xc0, xc1, yc0, yc1;
  bilinear_weights(W, cx, cy, w00, w01, w10, w11, xc0, xc1, yc0, yc1);
  const __half* b00 = pl + ((size_t)(yc0 * W + xc0) * FDIM + j8);
  const __half* b01 = pl + ((size_t)(yc0 * W + xc1) * FDIM + j8);
  const __half* b10 = pl + ((size_t)(yc1 * W + xc0) * FDIM + j8);
  const __half* b11 = pl + ((size_t)(yc1 * W + xc1) * FDIM + j8);
  H8 v00, v01, v10, v11;
  v00.u = *(const uint4*)b00;
  v01.u = *(const uint4*)b01;
  v10.u = *(const uint4*)b10;
  v11.u = *(const uint4*)b11;
#pragma unroll
  for (int k = 0; k < 8; ++k) {
    acc[k] += w00 * __half2float(v00.h[k]) + w01 * __half2float(v01.h[k]) +
              w10 * __half2float(v10.h[k]) + w11 * __half2float(v11.h[k]);
  }
}

__device__ __forceinline__ void sample8_d(const float* __restrict__ pl, int W,
                                          float cx, float cy, int j8, float acc[8]) {
  float w00, w01, w10, w11;
  int xc0, xc1, yc0, yc1;
  bilinear_weights(W, cx, cy, w00, w01, w10, w11, xc0, xc1, yc0, yc1);
  const size_t SS = (size_t)W * W;
  const int i00 = yc0 * W + xc0, i01 = yc0 * W + xc1;
  const int i10 = yc1 * W + xc0, i11 = yc1 * W + xc1;
#pragma unroll
  for (int k = 0; k < 8; ++k) {
    const size_t co = (size_t)(j8 + k) * SS;
    acc[k] += w00 * pl[co + i00] + w01 * pl[co + i01] +
              w10 * pl[co + i10] + w11 * pl[co + i11];
  }
}

struct PlanesH { const __half* p[9]; };
struct PlanesF { const float* p[9]; };

// ---------- main sampling kernel (fp16 transposed planes, sorted order) ----------
__global__ __launch_bounds__(256) void sample_kernel(const float* __restrict__ x,
                                                     const float* __restrict__ scale,
                                                     const unsigned* __restrict__ breaks,
                                                     const unsigned* __restrict__ order,
                                                     PlanesH tp, float* __restrict__ out) {
  const int t = blockIdx.x * 256 + threadIdx.x;   // exact grid: NPTS*8 threads
  const int slot = t >> 3;
  const int p = (int)order[slot];
  const int j8 = (t & 7) * 8;
  const float s0 = scale[0], s1 = scale[1], s2 = scale[2];
  const float xs0 = x[p * 3 + 0] * s0;
  const float xs1 = x[p * 3 + 1] * s1;
  const float xs2 = x[p * 3 + 2] * s2;
  unsigned b1 = breaks[0]; if (b1 >= NPTS) b1 = 0;
  unsigned b2 = breaks[1]; if (b2 >= NPTS) b2 = 0;
  const unsigned pu = (unsigned)p;
  const int level = (pu < b1) ? 0 : ((pu < b2) ? 1 : 2);
  float acc[8];
#pragma unroll
  for (int k = 0; k < 8; ++k) acc[k] = 0.0f;
  sample8_t(tp.p[0], 512, xs0, xs1, j8, acc);  // xy: (x,y)
  sample8_t(tp.p[1], 512, xs1, xs2, j8, acc);  // yz: (y,z)
  sample8_t(tp.p[2], 512, xs0, xs2, j8, acc);  // xz: (x,z)
  if (level >= 1) {
    sample8_t(tp.p[3], 256, xs0, xs1, j8, acc);
    sample8_t(tp.p[4], 256, xs1, xs2, j8, acc);
    sample8_t(tp.p[5], 256, xs0, xs2, j8, acc);
  }
  if (level >= 2) {
    sample8_t(tp.p[6], 128, xs0, xs1, j8, acc);
    sample8_t(tp.p[7], 128, xs1, xs2, j8, acc);
    sample8_t(tp.p[8], 128, xs0, xs2, j8, acc);
  }
  float* o = out + (size_t)p * FDIM + j8;
  vfloat4 lo = {acc[0], acc[1], acc[2], acc[3]};
  vfloat4 hi = {acc[4], acc[5], acc[6], acc[7]};
  __builtin_nontemporal_store(lo, (vfloat4*)o);
  __builtin_nontemporal_store(hi, (vfloat4*)(o + 4));
}

// ---------- fallback: sample directly from fp32 [C][H][W], unsorted ----------
__global__ __launch_bounds__(256) void sample_kernel_direct(const float* __restrict__ x,
                                                            const float* __restrict__ scale,
                                                            const unsigned* __restrict__ breaks,
                                                            PlanesF tp, float* __restrict__ out) {
  const int t = blockIdx.x * 256 + threadIdx.x;
  const int p = t >> 3;
  const int j8 = (t & 7) * 8;
  const float s0 = scale[0], s1 = scale[1], s2 = scale[2];
  const float xs0 = x[p * 3 + 0] * s0;
  const float xs1 = x[p * 3 + 1] * s1;
  const float xs2 = x[p * 3 + 2] * s2;
  unsigned b1 = breaks[0]; if (b1 >= NPTS) b1 = 0;
  unsigned b2 = breaks[1]; if (b2 >= NPTS) b2 = 0;
  const unsigned pu = (unsigned)p;
  const int level = (pu < b1) ? 0 : ((pu < b2) ? 1 : 2);
  float acc[8];
#pragma unroll
  for (int k = 0; k < 8; ++k) acc[k] = 0.0f;
  sample8_d(tp.p[0], 512, xs0, xs1, j8, acc);
  sample8_d(tp.p[1], 512, xs1, xs2, j8, acc);
  sample8_d(tp.p[2], 512, xs0, xs2, j8, acc);
  if (level >= 1) {
    sample8_d(tp.p[3], 256, xs0, xs1, j8, acc);
    sample8_d(tp.p[4], 256, xs1, xs2, j8, acc);
    sample8_d(tp.p[5], 256, xs0, xs2, j8, acc);
  }
  if (level >= 2) {
    sample8_d(tp.p[6], 128, xs0, xs1, j8, acc);
    sample8_d(tp.p[7], 128, xs1, xs2, j8, acc);
    sample8_d(tp.p[8], 128, xs0, xs2, j8, acc);
  }
  float4* o4 = (float4*)(out + (size_t)p * FDIM + j8);
  o4[0] = make_float4(acc[0], acc[1], acc[2], acc[3]);
  o4[1] = make_float4(acc[4], acc[5], acc[6], acc[7]);
}

extern "C" void kernel_launch(void* const* d_in, const int* in_sizes, int n_in,
                              void* d_out, int out_size, void* d_ws, size_t ws_size,
                              hipStream_t stream) {
  const float* x = (const float*)d_in[0];
  const float* rays_o = (const float*)d_in[1];
  const float* scale = (const float*)d_in[2];
  const float* pl32[9];
  for (int i = 0; i < 9; ++i) pl32[i] = (const float*)d_in[3 + i];
  float* out = (float*)d_out;

  unsigned char* ws = (unsigned char*)d_ws;
  // ws layout: breaks @0 (8B) | hist @256 (128 KB) | order @131328 (1 MB) | planes @1179904
  unsigned* breaks = (unsigned*)ws;
  unsigned* hist = (unsigned*)(ws + 256);
  unsigned* order = (unsigned*)(ws + 256 + NCELL * 4);
  const size_t planes_off = 256 + (size_t)NCELL * 4 + (size_t)NPTS * 4;

  (void)hipMemsetAsync(d_ws, 0xFF, 8, stream);                 // breaks sentinel
  break_kernel<<<256, 256, 0, stream>>>(x, rays_o, scale, breaks);

  const int Ss[3] = {512, 256, 128};
  size_t need = planes_off;
  for (int l = 0; l < 3; ++l) need += 3 * (size_t)Ss[l] * Ss[l] * FDIM * sizeof(__half);

  if (ws_size >= need) {
    // spatial counting sort
    (void)hipMemsetAsync(hist, 0, NCELL * 4, stream);
    hist_kernel<<<NPTS / 256, 256, 0, stream>>>(x, scale, hist);
    scan_kernel<<<1, 256, 0, stream>>>(hist);
    scatter_kernel<<<NPTS / 256, 256, 0, stream>>>(x, scale, hist, order);

    PlanesH tp;
    TransposeArgs ta;
    size_t off = planes_off;
    int tiles_acc = 0;
    for (int l = 0; l < 3; ++l) {
      const int S = Ss[l];
      const int SS = S * S;
      for (int o = 0; o < 3; ++o) {
        const int i = l * 3 + o;
        __half* dst = (__half*)(ws + off);
        tp.p[i] = dst;
        ta.src[i] = pl32[i];
        ta.dst[i] = dst;
        ta.SS[i] = SS;
        tiles_acc += SS / 64;
        ta.tile_hi[i] = tiles_acc;
        off += (size_t)SS * FDIM * sizeof(__half);
      }
    }
    transpose_all<<<tiles_acc, 256, 0, stream>>>(ta);
    sample_kernel<<<(NPTS * 8) / 256, 256, 0, stream>>>(x, scale, breaks, order, tp, out);
  } else {
    PlanesF tf;
    for (int i = 0; i < 9; ++i) tf.p[i] = pl32[i];
    sample_kernel_direct<<<(NPTS * 8) / 256, 256, 0, stream>>>(x, scale, breaks, tf, out);
  }
}

// Round 5
// 429.030 us; speedup vs baseline: 1.0898x; 1.0205x over previous
//
#include <hip/hip_runtime.h>
#include <hip/hip_fp16.h>

#define NPTS 262144
#define FDIM 64
#define NCELL 32768  // 32^3 Morton cells

typedef float vfloat4 __attribute__((ext_vector_type(4)));

// ---------- break-finding kernel ----------
__global__ __launch_bounds__(256) void break_kernel(const float* __restrict__ x,
                                                    const float* __restrict__ rays_o,
                                                    const float* __restrict__ scale,
                                                    unsigned* __restrict__ breaks) {
  const unsigned t = blockIdx.x * 256u + threadIdx.x;  // 256 blocks x 256 threads
  const float r0 = rays_o[0], r1 = rays_o[1], r2 = rays_o[2];
  const float s0 = scale[0], s1 = scale[1], s2 = scale[2];
  unsigned b1 = 0xFFFFFFFFu, b2 = 0xFFFFFFFFu;
  for (unsigned p = t; p < NPTS; p += 65536u) {
    const float dx = r0 - x[p * 3 + 0] * s0;
    const float dy = r1 - x[p * 3 + 1] * s1;
    const float dz = r2 - x[p * 3 + 2] * s2;
    const float d = sqrtf(__fadd_rn(__fadd_rn(__fmul_rn(dx, dx), __fmul_rn(dy, dy)),
                                    __fmul_rn(dz, dz)));
    if (d > 1.5f) b1 = min(b1, p);
    if (d > 2.0f) b2 = min(b2, p);
  }
  __shared__ unsigned sb1[256];
  __shared__ unsigned sb2[256];
  sb1[threadIdx.x] = b1;
  sb2[threadIdx.x] = b2;
  __syncthreads();
  for (int s = 128; s > 0; s >>= 1) {
    if ((int)threadIdx.x < s) {
      sb1[threadIdx.x] = min(sb1[threadIdx.x], sb1[threadIdx.x + s]);
      sb2[threadIdx.x] = min(sb2[threadIdx.x], sb2[threadIdx.x + s]);
    }
    __syncthreads();
  }
  if (threadIdx.x == 0) {
    atomicMin(&breaks[0], sb1[0]);
    atomicMin(&breaks[1], sb2[0]);
  }
}

// ---------- Morton cell key ----------
__device__ __forceinline__ unsigned part5(unsigned v) {
  v &= 31u;
  v = (v | (v << 8)) & 0x100Fu;
  v = (v | (v << 4)) & 0x10C3u;
  v = (v | (v << 2)) & 0x1249u;
  return v;
}

__device__ __forceinline__ unsigned cell_key(float x0, float x1, float x2) {
  const int cx = min(max((int)((x0 + 1.0f) * 16.0f), 0), 31);
  const int cy = min(max((int)((x1 + 1.0f) * 16.0f), 0), 31);
  const int cz = min(max((int)((x2 + 1.0f) * 16.0f), 0), 31);
  return part5((unsigned)cx) | (part5((unsigned)cy) << 1) | (part5((unsigned)cz) << 2);
}

// ---------- counting-sort kernels ----------
__global__ __launch_bounds__(256) void hist_kernel(const float* __restrict__ x,
                                                   const float* __restrict__ scale,
                                                   unsigned* __restrict__ hist) {
  const unsigned t = blockIdx.x * 256u + threadIdx.x;  // NPTS threads
  const float s0 = scale[0], s1 = scale[1], s2 = scale[2];
  const unsigned key = cell_key(x[t * 3 + 0] * s0, x[t * 3 + 1] * s1, x[t * 3 + 2] * s2);
  atomicAdd(&hist[key], 1u);
}

// Parallel exclusive scan over NCELL entries: 128 blocks x 256 cells each.
__global__ __launch_bounds__(256) void scan1_kernel(unsigned* __restrict__ hist,
                                                    unsigned* __restrict__ partials) {
  const int cell = blockIdx.x * 256 + threadIdx.x;
  const int tid = threadIdx.x;
  const unsigned h = hist[cell];
  __shared__ unsigned ls[256];
  ls[tid] = h;
  __syncthreads();
  for (int d = 1; d < 256; d <<= 1) {
    const unsigned add = (tid >= d) ? ls[tid - d] : 0u;
    __syncthreads();
    ls[tid] += add;
    __syncthreads();
  }
  hist[cell] = ls[tid] - h;  // local exclusive prefix
  if (tid == 255) partials[blockIdx.x] = ls[255];
}

__global__ __launch_bounds__(128) void scan2_kernel(unsigned* __restrict__ partials) {
  const int tid = threadIdx.x;  // 1 block x 128
  const unsigned h = partials[tid];
  __shared__ unsigned ls[128];
  ls[tid] = h;
  __syncthreads();
  for (int d = 1; d < 128; d <<= 1) {
    const unsigned add = (tid >= d) ? ls[tid - d] : 0u;
    __syncthreads();
    ls[tid] += add;
    __syncthreads();
  }
  partials[tid] = ls[tid] - h;  // exclusive
}

__global__ __launch_bounds__(256) void scan3_kernel(unsigned* __restrict__ hist,
                                                    const unsigned* __restrict__ partials) {
  const int cell = blockIdx.x * 256 + threadIdx.x;
  hist[cell] += partials[blockIdx.x];
}

__global__ __launch_bounds__(256) void scatter_kernel(const float* __restrict__ x,
                                                      const float* __restrict__ scale,
                                                      unsigned* __restrict__ offs,
                                                      unsigned* __restrict__ order) {
  const unsigned t = blockIdx.x * 256u + threadIdx.x;  // NPTS threads
  const float s0 = scale[0], s1 = scale[1], s2 = scale[2];
  const unsigned key = cell_key(x[t * 3 + 0] * s0, x[t * 3 + 1] * s1, x[t * 3 + 2] * s2);
  const unsigned pos = atomicAdd(&offs[key], 1u);
  order[pos] = t;
}

// ---------- fused transpose: 9x [C][S][S] fp32 -> [S*S][C] fp16 ----------
// Tile = 64 channels x 256 linear pixels: 1 KB contiguous per channel stream
// per block (DRAM-row friendly), 16 float4 loads in flight per wave.
struct TransposeArgs {
  const float* src[9];
  __half* dst[9];
  int tile_hi[9];  // inclusive prefix sum of tiles per plane
  int SS[9];
};

__global__ __launch_bounds__(256) void transpose_all(TransposeArgs a) {
  __shared__ __half lds[256 * 66];  // 33 KB, row stride 66 halves (132 B)
  const int tile = blockIdx.x;
  int pi = 0;
#pragma unroll
  for (int i = 0; i < 9; ++i) {
    if (tile >= a.tile_hi[i]) pi = i + 1;
  }
  const int lo = (pi == 0) ? 0 : a.tile_hi[pi - 1];
  const float* __restrict__ src = a.src[pi];
  __half* __restrict__ dst = a.dst[pi];
  const size_t SS = (size_t)a.SS[pi];
  const size_t p0 = (size_t)(tile - lo) * 256;

  const int t = threadIdx.x;
  // Phase 1: 64 KB global read as float4 (1 KB/wave-inst, contiguous per channel).
  const int px4 = t & 63;          // which float4 within the 256-px row
  const int cg = t >> 6;           // 0..3
#pragma unroll
  for (int it = 0; it < 16; ++it) {
    const int c = it * 4 + cg;
    const float4 v = *(const float4*)(src + (size_t)c * SS + p0 + (size_t)px4 * 4);
    lds[(px4 * 4 + 0) * 66 + c] = __float2half(v.x);
    lds[(px4 * 4 + 1) * 66 + c] = __float2half(v.y);
    lds[(px4 * 4 + 2) * 66 + c] = __float2half(v.z);
    lds[(px4 * 4 + 3) * 66 + c] = __float2half(v.w);
  }
  __syncthreads();
  // Phase 2: 32 KB global write as uint4 (8 halves; 1 KB/wave-inst contiguous).
  const int c8 = t & 7;
  const int pxo = t >> 3;          // 0..31
#pragma unroll
  for (int it = 0; it < 8; ++it) {
    const int px = it * 32 + pxo;
    const unsigned* w = (const unsigned*)(lds + px * 66 + c8 * 8);  // 4B-aligned
    uint4 v;
    v.x = w[0]; v.y = w[1]; v.z = w[2]; v.w = w[3];
    *(uint4*)(dst + (p0 + (size_t)px) * FDIM + c8 * 8) = v;         // 16B-aligned
  }
}

// ---------- bilinear sampling helpers ----------
union H8 { uint4 u; __half h[8]; };

__device__ __forceinline__ void bilinear_weights(int W, float cx, float cy,
                                                 float& w00, float& w01, float& w10, float& w11,
                                                 int& xc0, int& xc1, int& yc0, int& yc1) {
  const float Wm1 = (float)(W - 1);
  const float fx = (cx + 1.0f) * 0.5f * Wm1;
  const float fy = (cy + 1.0f) * 0.5f * Wm1;
  const float x0f = floorf(fx), y0f = floorf(fy);
  const float wx = fx - x0f, wy = fy - y0f;
  const int ix = (int)x0f, iy = (int)y0f;
  const int ix1 = ix + 1, iy1 = iy + 1;
  const bool vx0 = (ix >= 0) && (ix < W);
  const bool vx1 = (ix1 >= 0) && (ix1 < W);
  const bool vy0 = (iy >= 0) && (iy < W);
  const bool vy1 = (iy1 >= 0) && (iy1 < W);
  xc0 = min(max(ix, 0), W - 1);
  xc1 = min(max(ix1, 0), W - 1);
  yc0 = min(max(iy, 0), W - 1);
  yc1 = min(max(iy1, 0), W - 1);
  w00 = (1.0f - wx) * (1.0f - wy) * (float)(vx0 && vy0);
  w01 = wx * (1.0f - wy) * (float)(vx1 && vy0);
  w10 = (1.0f - wx) * wy * (float)(vx0 && vy1);
  w11 = wx * wy * (float)(vx1 && vy1);
}

__device__ __forceinline__ void sample8_t(const __half* __restrict__ pl, int W,
                                          float cx, float cy, int j8, float acc[8]) {
  float w00, w01, w10, w11;
  int xc0, xc1, yc0, yc1;
  bilinear_weights(W, cx, cy, w00, w01, w10, w11, xc0, xc1, yc0, yc1);
  const __half* b00 = pl + ((size_t)(yc0 * W + xc0) * FDIM + j8);
  const __half* b01 = pl + ((size_t)(yc0 * W + xc1) * FDIM + j8);
  const __half* b10 = pl + ((size_t)(yc1 * W + xc0) * FDIM + j8);
  const __half* b11 = pl + ((size_t)(yc1 * W + xc1) * FDIM + j8);
  H8 v00, v01, v10, v11;
  v00.u = *(const uint4*)b00;
  v01.u = *(const uint4*)b01;
  v10.u = *(const uint4*)b10;
  v11.u = *(const uint4*)b11;
#pragma unroll
  for (int k = 0; k < 8; ++k) {
    acc[k] += w00 * __half2float(v00.h[k]) + w01 * __half2float(v01.h[k]) +
              w10 * __half2float(v10.h[k]) + w11 * __half2float(v11.h[k]);
  }
}

__device__ __forceinline__ void sample8_d(const float* __restrict__ pl, int W,
                                          float cx, float cy, int j8, float acc[8]) {
  float w00, w01, w10, w11;
  int xc0, xc1, yc0, yc1;
  bilinear_weights(W, cx, cy, w00, w01, w10, w11, xc0, xc1, yc0, yc1);
  const size_t SS = (size_t)W * W;
  const int i00 = yc0 * W + xc0, i01 = yc0 * W + xc1;
  const int i10 = yc1 * W + xc0, i11 = yc1 * W + xc1;
#pragma unroll
  for (int k = 0; k < 8; ++k) {
    const size_t co = (size_t)(j8 + k) * SS;
    acc[k] += w00 * pl[co + i00] + w01 * pl[co + i01] +
              w10 * pl[co + i10] + w11 * pl[co + i11];
  }
}

struct PlanesH { const __half* p[9]; };
struct PlanesF { const float* p[9]; };

// ---------- main sampling kernel (fp16 transposed planes, sorted order) ----------
__global__ __launch_bounds__(256) void sample_kernel(const float* __restrict__ x,
                                                     const float* __restrict__ scale,
                                                     const unsigned* __restrict__ breaks,
                                                     const unsigned* __restrict__ order,
                                                     PlanesH tp, float* __restrict__ out) {
  const int t = blockIdx.x * 256 + threadIdx.x;   // exact grid: NPTS*8 threads
  const int slot = t >> 3;
  const int p = (int)order[slot];
  const int j8 = (t & 7) * 8;
  const float s0 = scale[0], s1 = scale[1], s2 = scale[2];
  const float xs0 = x[p * 3 + 0] * s0;
  const float xs1 = x[p * 3 + 1] * s1;
  const float xs2 = x[p * 3 + 2] * s2;
  unsigned b1 = breaks[0]; if (b1 >= NPTS) b1 = 0;
  unsigned b2 = breaks[1]; if (b2 >= NPTS) b2 = 0;
  const unsigned pu = (unsigned)p;
  const int level = (pu < b1) ? 0 : ((pu < b2) ? 1 : 2);
  float acc[8];
#pragma unroll
  for (int k = 0; k < 8; ++k) acc[k] = 0.0f;
  sample8_t(tp.p[0], 512, xs0, xs1, j8, acc);  // xy: (x,y)
  sample8_t(tp.p[1], 512, xs1, xs2, j8, acc);  // yz: (y,z)
  sample8_t(tp.p[2], 512, xs0, xs2, j8, acc);  // xz: (x,z)
  if (level >= 1) {
    sample8_t(tp.p[3], 256, xs0, xs1, j8, acc);
    sample8_t(tp.p[4], 256, xs1, xs2, j8, acc);
    sample8_t(tp.p[5], 256, xs0, xs2, j8, acc);
  }
  if (level >= 2) {
    sample8_t(tp.p[6], 128, xs0, xs1, j8, acc);
    sample8_t(tp.p[7], 128, xs1, xs2, j8, acc);
    sample8_t(tp.p[8], 128, xs0, xs2, j8, acc);
  }
  float* o = out + (size_t)p * FDIM + j8;
  vfloat4 lo = {acc[0], acc[1], acc[2], acc[3]};
  vfloat4 hi = {acc[4], acc[5], acc[6], acc[7]};
  __builtin_nontemporal_store(lo, (vfloat4*)o);
  __builtin_nontemporal_store(hi, (vfloat4*)(o + 4));
}

// ---------- fallback: sample directly from fp32 [C][H][W], unsorted ----------
__global__ __launch_bounds__(256) void sample_kernel_direct(const float* __restrict__ x,
                                                            const float* __restrict__ scale,
                                                            const unsigned* __restrict__ breaks,
                                                            PlanesF tp, float* __restrict__ out) {
  const int t = blockIdx.x * 256 + threadIdx.x;
  const int p = t >> 3;
  const int j8 = (t & 7) * 8;
  const float s0 = scale[0], s1 = scale[1], s2 = scale[2];
  const float xs0 = x[p * 3 + 0] * s0;
  const float xs1 = x[p * 3 + 1] * s1;
  const float xs2 = x[p * 3 + 2] * s2;
  unsigned b1 = breaks[0]; if (b1 >= NPTS) b1 = 0;
  unsigned b2 = breaks[1]; if (b2 >= NPTS) b2 = 0;
  const unsigned pu = (unsigned)p;
  const int level = (pu < b1) ? 0 : ((pu < b2) ? 1 : 2);
  float acc[8];
#pragma unroll
  for (int k = 0; k < 8; ++k) acc[k] = 0.0f;
  sample8_d(tp.p[0], 512, xs0, xs1, j8, acc);
  sample8_d(tp.p[1], 512, xs1, xs2, j8, acc);
  sample8_d(tp.p[2], 512, xs0, xs2, j8, acc);
  if (level >= 1) {
    sample8_d(tp.p[3], 256, xs0, xs1, j8, acc);
    sample8_d(tp.p[4], 256, xs1, xs2, j8, acc);
    sample8_d(tp.p[5], 256, xs0, xs2, j8, acc);
  }
  if (level >= 2) {
    sample8_d(tp.p[6], 128, xs0, xs1, j8, acc);
    sample8_d(tp.p[7], 128, xs1, xs2, j8, acc);
    sample8_d(tp.p[8], 128, xs0, xs2, j8, acc);
  }
  float4* o4 = (float4*)(out + (size_t)p * FDIM + j8);
  o4[0] = make_float4(acc[0], acc[1], acc[2], acc[3]);
  o4[1] = make_float4(acc[4], acc[5], acc[6], acc[7]);
}

extern "C" void kernel_launch(void* const* d_in, const int* in_sizes, int n_in,
                              void* d_out, int out_size, void* d_ws, size_t ws_size,
                              hipStream_t stream) {
  const float* x = (const float*)d_in[0];
  const float* rays_o = (const float*)d_in[1];
  const float* scale = (const float*)d_in[2];
  const float* pl32[9];
  for (int i = 0; i < 9; ++i) pl32[i] = (const float*)d_in[3 + i];
  float* out = (float*)d_out;

  unsigned char* ws = (unsigned char*)d_ws;
  // ws layout: breaks @0 (8B) | partials @128 (512B) | hist @1024 (128 KB) |
  //            order @132096 (1 MB) | planes @1180672
  unsigned* breaks = (unsigned*)ws;
  unsigned* partials = (unsigned*)(ws + 128);
  unsigned* hist = (unsigned*)(ws + 1024);
  unsigned* order = (unsigned*)(ws + 1024 + NCELL * 4);
  const size_t planes_off = 1024 + (size_t)NCELL * 4 + (size_t)NPTS * 4;

  (void)hipMemsetAsync(d_ws, 0xFF, 8, stream);                 // breaks sentinel
  break_kernel<<<256, 256, 0, stream>>>(x, rays_o, scale, breaks);

  const int Ss[3] = {512, 256, 128};
  size_t need = planes_off;
  for (int l = 0; l < 3; ++l) need += 3 * (size_t)Ss[l] * Ss[l] * FDIM * sizeof(__half);

  if (ws_size >= need) {
    // spatial counting sort (parallel scan)
    (void)hipMemsetAsync(hist, 0, NCELL * 4, stream);
    hist_kernel<<<NPTS / 256, 256, 0, stream>>>(x, scale, hist);
    scan1_kernel<<<NCELL / 256, 256, 0, stream>>>(hist, partials);
    scan2_kernel<<<1, 128, 0, stream>>>(partials);
    scan3_kernel<<<NCELL / 256, 256, 0, stream>>>(hist, partials);
    scatter_kernel<<<NPTS / 256, 256, 0, stream>>>(x, scale, hist, order);

    PlanesH tp;
    TransposeArgs ta;
    size_t off = planes_off;
    int tiles_acc = 0;
    for (int l = 0; l < 3; ++l) {
      const int S = Ss[l];
      const int SS = S * S;
      for (int o = 0; o < 3; ++o) {
        const int i = l * 3 + o;
        __half* dst = (__half*)(ws + off);
        tp.p[i] = dst;
        ta.src[i] = pl32[i];
        ta.dst[i] = dst;
        ta.SS[i] = SS;
        tiles_acc += SS / 256;
        ta.tile_hi[i] = tiles_acc;
        off += (size_t)SS * FDIM * sizeof(__half);
      }
    }
    transpose_all<<<tiles_acc, 256, 0, stream>>>(ta);
    sample_kernel<<<(NPTS * 8) / 256, 256, 0, stream>>>(x, scale, breaks, order, tp, out);
  } else {
    PlanesF tf;
    for (int i = 0; i < 9; ++i) tf.p[i] = pl32[i];
    sample_kernel_direct<<<(NPTS * 8) / 256, 256, 0, stream>>>(x, scale, breaks, tf, out);
  }
}